// Round 6
// baseline (97.990 us; speedup 1.0000x reference)
//
#include <hip/hip_runtime.h>

#define NGRID 257
#define LDS_PITCH 260                      // halfs per row; 520 B stride (65*8B)
#define LDS_BYTES (LDS_PITCH * NGRID * 2)  // 133640 B < 160 KiB
#define BLOCK 1024
#define GRID 256
#define ITERS 8                            // 2,097,152 pairs == GRID*BLOCK*ITERS exactly

typedef _Float16 half4_t __attribute__((ext_vector_type(4)));
typedef float    f2v     __attribute__((ext_vector_type(2)));  // native vec for nt-store

// 4-byte-aligned float4 view (coe rows have odd stride 257)
struct __attribute__((packed, aligned(4))) f4u { float x, y, z, w; };

// One point's raw fragments: 5 rows x 16B (cols 0..7 of the patch; we use 0..4).
// lo/hi are adjacent 8B reads -> DS combiner fuses into ds_read2_b64 (1 instr/row).
struct PtFrag {
    half4_t lo[5];   // cols 0..3
    half4_t hi[5];   // cols 4..7 (only [0] used)
};

__device__ __forceinline__ void lag_basis(float t, float b[5]) {
    float f0 = t;
    float f1 = t - 1.0f;
    float f2 = t - 2.0f;
    float f3 = t - 3.0f;
    float f4 = t - 4.0f;
    float p01 = f0 * f1;
    float p12 = f1 * f2;
    float p23 = f2 * f3;
    float p34 = f3 * f4;
    b[0] = p12 * p34 * (1.0f / 24.0f);
    b[1] = f0 * f2 * p34 * (-1.0f / 6.0f);
    b[2] = p01 * p34 * (1.0f / 4.0f);
    b[3] = p01 * f2 * f4 * (-1.0f / 6.0f);
    b[4] = p01 * p23 * (1.0f / 24.0f);
}

__device__ __forceinline__ int pt_off(float x0, float x1) {
    float u0 = x0 * 64.0f, u1 = x1 * 64.0f;
    float c0 = fminf(fmaxf(floorf(u0), 0.0f), 63.0f);
    float c1 = fminf(fmaxf(floorf(u1), 0.0f), 63.0f);
    return ((int)c0 * 4) * LDS_PITCH + ((int)c1 * 4);
}

// Issue 5 fused 16B row reads for one point (5 ds_read2_b64 expected).
__device__ __forceinline__ void stage_point(const _Float16* __restrict__ lds,
                                            int off, PtFrag& f) {
    const _Float16* base = lds + off;   // 8B-aligned (520B rows, 8B col base)
#pragma unroll
    for (int i = 0; i < 5; ++i) {
        const _Float16* rp = base + i * LDS_PITCH;
        f.lo[i] = *(const half4_t*)rp;
        f.hi[i] = *(const half4_t*)(rp + 4);
    }
}

// Consume one point's fragments; recomputes basis (pure VALU, fills wait window).
__device__ __forceinline__ float eval_pt(const PtFrag& f, float x0, float x1) {
    float u0 = x0 * 64.0f, u1 = x1 * 64.0f;
    float c0 = fminf(fmaxf(floorf(u0), 0.0f), 63.0f);
    float c1 = fminf(fmaxf(floorf(u1), 0.0f), 63.0f);
    float b0[5], b1[5];
    lag_basis((u0 - c0) * 4.0f, b0);
    lag_basis((u1 - c1) * 4.0f, b1);
    float acc = 0.0f;
#pragma unroll
    for (int i = 0; i < 5; ++i) {
        float rd = (float)f.lo[i][0] * b1[0];          // mad_mix-fusible
        rd = fmaf((float)f.lo[i][1], b1[1], rd);
        rd = fmaf((float)f.lo[i][2], b1[2], rd);
        rd = fmaf((float)f.lo[i][3], b1[3], rd);
        rd = fmaf((float)f.hi[i][0], b1[4], rd);
        acc = fmaf(b0[i], rd, acc);
    }
    return acc;
}

__launch_bounds__(BLOCK, 4)   // VGPR<=128 so the single 133KB-LDS block keeps 16 waves/CU
__global__ void lagrange_kernel(const float* __restrict__ inputs,
                                const float* __restrict__ coe,
                                float* __restrict__ out,
                                int npairs) {
    extern __shared__ _Float16 lds[];

    // --- staged table load: float4 (4B-aligned) -> half4 ds_write_b64 ---
    for (int g = threadIdx.x; g < NGRID * 65; g += BLOCK) {
        int r = g / 65;                 // constant divisor -> magic mul
        int c4 = (g - r * 65) * 4;
        if (c4 < 256) {
            f4u q = *(const f4u*)(coe + r * NGRID + c4);
            half4_t h = { (_Float16)q.x, (_Float16)q.y,
                          (_Float16)q.z, (_Float16)q.w };
            *(half4_t*)(lds + r * LDS_PITCH + c4) = h;
        } else {
            lds[r * LDS_PITCH + 256] = (_Float16)coe[r * NGRID + 256];
        }
    }
    __syncthreads();

    const float4* __restrict__ in4 = (const float4*)inputs;  // 2 points / float4
    f2v* __restrict__ out2 = (f2v*)out;
    const int tid = blockIdx.x * BLOCK + threadIdx.x;
    const int stride = GRID * BLOCK;
    (void)npairs;  // npairs == GRID*BLOCK*ITERS exactly -> no bounds checks

    // --- depth-1 pair pipeline: stage k+1's 10 fused reads, then eval pair k.
    // No sched_barriers (proven neutral R5): scheduler may interleave freely.
    float4 va, vb, vc;      // rolling input window
    PtFrag fA[2], fB[2];    // double-buffered fragments (80 VGPRs in flight)

    va = in4[tid];
    vb = in4[tid + stride];
    stage_point(lds, pt_off(va.x, va.y), fA[0]);
    stage_point(lds, pt_off(va.z, va.w), fB[0]);

#pragma unroll
    for (int k = 0; k < ITERS; ++k) {
        if (k + 2 < ITERS) vc = in4[tid + (k + 2) * stride];
        if (k + 1 < ITERS) {
            stage_point(lds, pt_off(vb.x, vb.y), fA[(k + 1) & 1]);
            stage_point(lds, pt_off(vb.z, vb.w), fB[(k + 1) & 1]);
        }
        f2v r;
        r.x = eval_pt(fA[k & 1], va.x, va.y);
        r.y = eval_pt(fB[k & 1], va.z, va.w);
        __builtin_nontemporal_store(r, &out2[tid + k * stride]);
        va = vb;
        vb = vc;
    }
}

extern "C" void kernel_launch(void* const* d_in, const int* in_sizes, int n_in,
                              void* d_out, int out_size, void* d_ws, size_t ws_size,
                              hipStream_t stream) {
    const float* inputs = (const float*)d_in[0];   // (2048,2048,2) f32
    const float* coe    = (const float*)d_in[1];   // (257,257) f32
    float* out = (float*)d_out;                    // (2048,2048) f32
    int npairs = out_size >> 1;                    // 2,097,152

    (void)hipFuncSetAttribute((const void*)lagrange_kernel,
                              hipFuncAttributeMaxDynamicSharedMemorySize,
                              LDS_BYTES);

    dim3 grid(GRID), block(BLOCK);   // 1 block/CU (LDS-limited), 16 waves/CU
    hipLaunchKernelGGL(lagrange_kernel, grid, block, LDS_BYTES, stream,
                       inputs, coe, out, npairs);
}

// Round 7
// 94.823 us; speedup vs baseline: 1.0334x; 1.0334x over previous
//
#include <hip/hip_runtime.h>

#define NGRID 257
#define LDS_PITCH 260                      // halfs per row; 520 B stride
#define LDS_BYTES (LDS_PITCH * NGRID * 2)  // 133640 B < 160 KiB
#define BLOCK 1024
#define GRID 256
#define ITERS 16                           // 4,194,304 points == GRID*BLOCK*ITERS exactly

typedef _Float16 half2_t __attribute__((ext_vector_type(2)));
typedef _Float16 half4_t __attribute__((ext_vector_type(4)));

// 4-byte-aligned float4 view (coe rows have odd stride 257)
struct __attribute__((packed, aligned(4))) f4u { float x, y, z, w; };

// One point's fragments: 5 rows x (cols0-3 b64, cols4-5 b32) = 15 VGPRs.
// Small on purpose: 3 buffers in flight for a depth-2 pipeline.
struct PtFrag {
    half4_t lo[5];
    half2_t hi[5];
};

__device__ __forceinline__ void lag_basis(float t, float b[5]) {
    float f0 = t;
    float f1 = t - 1.0f;
    float f2 = t - 2.0f;
    float f3 = t - 3.0f;
    float f4 = t - 4.0f;
    float p01 = f0 * f1;
    float p12 = f1 * f2;
    float p23 = f2 * f3;
    float p34 = f3 * f4;
    b[0] = p12 * p34 * (1.0f / 24.0f);
    b[1] = f0 * f2 * p34 * (-1.0f / 6.0f);
    b[2] = p01 * p34 * (1.0f / 4.0f);
    b[3] = p01 * f2 * f4 * (-1.0f / 6.0f);
    b[4] = p01 * p23 * (1.0f / 24.0f);
}

__device__ __forceinline__ int pt_off(float x0, float x1) {
    float u0 = x0 * 64.0f, u1 = x1 * 64.0f;
    float c0 = fminf(fmaxf(floorf(u0), 0.0f), 63.0f);
    float c1 = fminf(fmaxf(floorf(u1), 0.0f), 63.0f);
    return ((int)c0 * 4) * LDS_PITCH + ((int)c1 * 4);
}

// Issue 10 LDS reads for one point (5x ds_read_b64 + 5x ds_read_b32).
__device__ __forceinline__ void stage_point(const _Float16* __restrict__ lds,
                                            int off, PtFrag& f) {
    const _Float16* base = lds + off;   // 8B-aligned (520B rows, 8B col base)
#pragma unroll
    for (int i = 0; i < 5; ++i)
        f.lo[i] = *(const half4_t*)(base + i * LDS_PITCH);
#pragma unroll
    for (int i = 0; i < 5; ++i)
        f.hi[i] = *(const half2_t*)(base + i * LDS_PITCH + 4);
}

// Consume one point's fragments; recomputes basis (pure VALU).
__device__ __forceinline__ float eval_pt(const PtFrag& f, float x0, float x1) {
    float u0 = x0 * 64.0f, u1 = x1 * 64.0f;
    float c0 = fminf(fmaxf(floorf(u0), 0.0f), 63.0f);
    float c1 = fminf(fmaxf(floorf(u1), 0.0f), 63.0f);
    float b0[5], b1[5];
    lag_basis((u0 - c0) * 4.0f, b0);
    lag_basis((u1 - c1) * 4.0f, b1);
    float acc = 0.0f;
#pragma unroll
    for (int i = 0; i < 5; ++i) {
        float rd = (float)f.lo[i][0] * b1[0];
        rd = fmaf((float)f.lo[i][1], b1[1], rd);
        rd = fmaf((float)f.lo[i][2], b1[2], rd);
        rd = fmaf((float)f.lo[i][3], b1[3], rd);
        rd = fmaf((float)f.hi[i][0], b1[4], rd);
        acc = fmaf(b0[i], rd, acc);
    }
    return acc;
}

__launch_bounds__(BLOCK, 4)   // VGPR<=128: single 133KB-LDS block keeps 16 waves/CU
__global__ void lagrange_kernel(const float* __restrict__ inputs,
                                const float* __restrict__ coe,
                                float* __restrict__ out,
                                int npts) {
    extern __shared__ _Float16 lds[];

    // --- staged table load: float4 (4B-aligned) -> half4 ds_write_b64 ---
    for (int g = threadIdx.x; g < NGRID * 65; g += BLOCK) {
        int r = g / 65;                 // constant divisor -> magic mul
        int c4 = (g - r * 65) * 4;
        if (c4 < 256) {
            f4u q = *(const f4u*)(coe + r * NGRID + c4);
            half4_t h = { (_Float16)q.x, (_Float16)q.y,
                          (_Float16)q.z, (_Float16)q.w };
            *(half4_t*)(lds + r * LDS_PITCH + c4) = h;
        } else {
            lds[r * LDS_PITCH + 256] = (_Float16)coe[r * NGRID + 256];
        }
    }
    __syncthreads();

    const float2* __restrict__ in2 = (const float2*)inputs;  // 1 point / float2
    const int tid = blockIdx.x * BLOCK + threadIdx.x;
    const int stride = GRID * BLOCK;
    (void)npts;   // npts == GRID*BLOCK*ITERS exactly -> no bounds checks

    // --- depth-2 pipeline: stage k+2's reads while consuming k ---
    float2 w0, w1, w2, w3;   // rolling input window (k, k+1, k+2, k+3)
    PtFrag f[3];             // 45 VGPRs of fragments in flight

    w0 = in2[tid];
    w1 = in2[tid + stride];
    w2 = in2[tid + 2 * stride];
    stage_point(lds, pt_off(w0.x, w0.y), f[0]);
    stage_point(lds, pt_off(w1.x, w1.y), f[1]);

#pragma unroll
    for (int k = 0; k < ITERS; ++k) {
        if (k + 3 < ITERS) w3 = in2[tid + (k + 3) * stride];
        if (k + 2 < ITERS) stage_point(lds, pt_off(w2.x, w2.y), f[(k + 2) % 3]);
        float r = eval_pt(f[k % 3], w0.x, w0.y);
        __builtin_nontemporal_store(r, &out[tid + k * stride]);
        w0 = w1;
        w1 = w2;
        w2 = w3;
    }
}

extern "C" void kernel_launch(void* const* d_in, const int* in_sizes, int n_in,
                              void* d_out, int out_size, void* d_ws, size_t ws_size,
                              hipStream_t stream) {
    const float* inputs = (const float*)d_in[0];   // (2048,2048,2) f32
    const float* coe    = (const float*)d_in[1];   // (257,257) f32
    float* out = (float*)d_out;                    // (2048,2048) f32
    int npts = out_size;                           // 4,194,304

    (void)hipFuncSetAttribute((const void*)lagrange_kernel,
                              hipFuncAttributeMaxDynamicSharedMemorySize,
                              LDS_BYTES);

    dim3 grid(GRID), block(BLOCK);   // 1 block/CU (LDS-limited), 16 waves/CU
    hipLaunchKernelGGL(lagrange_kernel, grid, block, LDS_BYTES, stream,
                       inputs, coe, out, npts);
}